// Round 8
// baseline (123.541 us; speedup 1.0000x reference)
//
#include <hip/hip_runtime.h>

// MHA forward, full-bf16 MFMA pipeline.
// ws layout (bytes): xb[8MB] | Wt[6MB: [3][1024][1024] bf16 N-major] | Wot[2MB]
//                    | qkv[24MB: Q,K:[B][H][T][64], V:[B][H][64][T]] | Y[8MB]

typedef short v8s __attribute__((ext_vector_type(8)));
typedef float v4f __attribute__((ext_vector_type(4)));

#define DEVI __device__ __forceinline__

#define B_SZ 2
#define T_SEQ 2048
#define NH 16
#define HS 64
#define CEMB 1024
#define MROWS (B_SZ * T_SEQ)   // 4096
#define KSZ 1024
// Q scale: 1/sqrt(64) * log2(e)  (attention softmax runs in exp2 domain)
#define SCALE_Q 0.18033688011112042f

DEVI unsigned short f2bf(float f) {
  union { float f; unsigned u; } c; c.f = f;
  unsigned u = c.u;
  unsigned r = (u + 0x7FFFu + ((u >> 16) & 1u)) >> 16;   // RNE
  return (unsigned short)r;
}

DEVI float exp2_fast(float x) {         // v_exp_f32 = 2^x
  float r;
  asm("v_exp_f32 %0, %1" : "=v"(r) : "v"(x));
  return r;
}

DEVI unsigned cvt_pk_bf16(float lo, float hi) {  // packs 2 f32 -> 2 bf16
  unsigned r;
  asm("v_cvt_pk_bf16_f32 %0, %1, %2" : "=v"(r) : "v"(lo), "v"(hi));
  return r;
}

// async global -> LDS, 16B per lane (wave-uniform LDS base + lane*16)
DEVI void gload_lds16(const void* g, void* l) {
  __builtin_amdgcn_global_load_lds(
      (const __attribute__((address_space(1))) void*)g,
      (__attribute__((address_space(3))) void*)l, 16, 0, 0);
}

// bijective XCD-contiguous block swizzle (requires nwg % 8 == 0)
DEVI int xcd_swz(int bid, int nwg) {
  int q = nwg >> 3;
  return (bid & 7) * q + (bid >> 3);
}

// ---------------- fused prep: x->bf16 + weight transposes (1 launch) -------
__global__ __launch_bounds__(256, 4) void prep_kernel(
    const float* __restrict__ x, const float* __restrict__ Wq,
    const float* __restrict__ Wk, const float* __restrict__ Wv,
    const float* __restrict__ Wo, unsigned short* __restrict__ xb,
    unsigned short* __restrict__ Wt, unsigned short* __restrict__ Wot) {
  int bid = blockIdx.x;
  if (bid < 2048) {
    int i = bid * 2048 + threadIdx.x * 8;
    float4 a = *(const float4*)(x + i);
    float4 b = *(const float4*)(x + i + 4);
    ushort4 o0, o1;
    o0.x = f2bf(a.x); o0.y = f2bf(a.y); o0.z = f2bf(a.z); o0.w = f2bf(a.w);
    o1.x = f2bf(b.x); o1.y = f2bf(b.y); o1.z = f2bf(b.z); o1.w = f2bf(b.w);
    *(ushort4*)(xb + i) = o0;
    *(ushort4*)(xb + i + 4) = o1;
    return;
  }
  __shared__ float tile[32][33];
  const float* in; unsigned short* out;
  int C, bx, by;
  if (bid < 5120) {
    int b2 = bid - 2048;
    int widx = b2 >> 10, rem = b2 & 1023;
    in = (widx == 0 ? Wq : (widx == 1 ? Wk : Wv));
    int z = rem >> 6;                     // head 0..15
    bx = rem & 1; by = (rem >> 1) & 31;
    C = 64;
    in += (size_t)z * 1024 * 64;
    out = Wt + ((size_t)widx << 20) + (size_t)z * 1024 * 64;
  } else {
    int rem = bid - 5120;
    C = 1024;
    bx = rem & 31; by = rem >> 5;
    in = Wo; out = Wot;
  }
  int c0 = bx * 32, r0 = by * 32;
  int tx = threadIdx.x & 31, ty = threadIdx.x >> 5;
#pragma unroll
  for (int j = 0; j < 4; ++j)
    tile[ty + j * 8][tx] = in[(size_t)(r0 + ty + j * 8) * C + c0 + tx];
  __syncthreads();
#pragma unroll
  for (int j = 0; j < 4; ++j)
    out[(size_t)(c0 + ty + j * 8) * 1024 + r0 + tx] = f2bf(tile[tx][ty + j * 8]);
}

// ===================== 256x256 8-phase GEMM (QKV) ==========================
// BM=BN=256, BK=64, 8 waves (2Mx4N), 512 thr; LDS 128KB: [A|B][slot0|1][h0|h1]
// halftile = [128 rows][64 cols] bf16 = 16KB, K-chunk XOR swizzle (c ^= row&7)
// via pre-swizzled global source + same XOR on ds_read (rule #21 involution).
// Per phase: {ds_read subtile || stage 1 halftile} barrier; lgkm(0); 16 MFMA
// (setprio-wrapped); barrier. vmcnt(2) only before ph0/ph4 (counted, T4).
DEVI void stage_half(const unsigned short* gbase, unsigned char* lbase,
                     int kt, int slot, int h) {
  const unsigned short* g = gbase + (size_t)h * (128 * KSZ) + kt * 64;
  unsigned char* l = lbase + slot * 32768 + h * 16384;
  gload_lds16(g, l);                       // rows 0-63 of half
  gload_lds16(g + 64 * KSZ, l + 8192);     // rows 64-127
}

template <int MQ>
DEVI void read_aq(const unsigned char* rA, int lg, int lr, v8s (&a)[4][2]) {
  const unsigned char* p = rA + MQ * 8192 + lr * 128;
#pragma unroll
  for (int m = 0; m < 4; ++m)
#pragma unroll
    for (int ks = 0; ks < 2; ++ks)
      a[m][ks] = *(const v8s*)(p + m * 2048 +
                               ((((ks << 2) + lg) ^ (lr & 7)) << 4));
}

template <int NQ>
DEVI void read_bq(const unsigned char* rB, int lg, int lr, v8s (&b)[4][2]) {
  const unsigned char* p = rB + NQ * 4096 + lr * 128;
#pragma unroll
  for (int j = 0; j < 2; ++j)
#pragma unroll
    for (int ks = 0; ks < 2; ++ks)
      b[NQ * 2 + j][ks] = *(const v8s*)(p + j * 2048 +
                                        ((((ks << 2) + lg) ^ (lr & 7)) << 4));
}

template <int MQ, int NQ>
DEVI void mfma_quad(const v8s (&a)[4][2], const v8s (&b)[4][2],
                    v4f (&acc)[8][4]) {
  __builtin_amdgcn_s_setprio(1);
#pragma unroll
  for (int m = 0; m < 4; ++m)
#pragma unroll
    for (int j = 0; j < 2; ++j)
#pragma unroll
      for (int ks = 0; ks < 2; ++ks)
        acc[MQ * 4 + m][NQ * 2 + j] = __builtin_amdgcn_mfma_f32_16x16x32_bf16(
            a[m][ks], b[NQ * 2 + j][ks], acc[MQ * 4 + m][NQ * 2 + j], 0, 0, 0);
  __builtin_amdgcn_s_setprio(0);
}

__global__ __launch_bounds__(512, 2) void gemm256(
    const unsigned short* __restrict__ A, const unsigned short* __restrict__ Bt,
    unsigned short* __restrict__ Cout, int nbx) {
  __shared__ __align__(16) unsigned char lds[131072];

  const int tid = threadIdx.x;
  const int lane = tid & 63, w = tid >> 6;
  const int wm = w >> 2, wn = w & 3;
  const int lr = lane & 15, lg = lane >> 4;
  const int wg = xcd_swz(blockIdx.x, gridDim.x);
  const int mb = (wg / nbx) * 256, nb = (wg % nbx) * 256;

  v4f acc[8][4];
  v4f zero = {0.f, 0.f, 0.f, 0.f};
#pragma unroll
  for (int i = 0; i < 8; ++i)
#pragma unroll
    for (int j = 0; j < 4; ++j) acc[i][j] = zero;

  // staging geometry: thread t -> row t>>3 (both loads), global chunk swizzled
  const int ts_row = tid >> 3;
  const int gch = (tid & 7) ^ (ts_row & 7);
  const unsigned short* gA = A + (size_t)(mb + ts_row) * KSZ + gch * 8;
  const unsigned short* gB = Bt + (size_t)(nb + ts_row) * KSZ + gch * 8;
  unsigned char* lA = lds + w * 1024;
  unsigned char* lB = lds + 65536 + w * 1024;

  // read bases (slot0; +32768 for slot1)
  const unsigned char* rA = lds + wm * 16384;
  const unsigned char* rB = lds + 65536 + (wn >> 1) * 16384 + (wn & 1) * 8192;

  v8s aq[4][2], bq[4][2];

  // prologue: stage A0h0, A0h1, B0h0, B0h1 (slot0), A1h0 (slot1)
  stage_half(gA, lA, 0, 0, 0);
  stage_half(gA, lA, 0, 0, 1);
  stage_half(gB, lB, 0, 0, 0);
  stage_half(gB, lB, 0, 0, 1);
  stage_half(gA, lA, 1, 1, 0);

  for (int it = 0; it < 8; ++it) {
    const int c = 2 * it;
    // W0: slot0 (K-tile c) fully landed for ALL waves; ph7's load may fly
    asm volatile("s_waitcnt vmcnt(2)" ::: "memory");
    __builtin_amdgcn_s_barrier();

    // ph0: read A-q0 + B-q01 (slot0); stage A(c+1)h1 -> slot1
    read_aq<0>(rA, lg, lr, aq);
    read_bq<0>(rB, lg, lr, bq);
    stage_half(gA, lA, c + 1, 1, 1);
    __builtin_amdgcn_s_barrier();
    asm volatile("s_waitcnt lgkmcnt(0)" ::: "memory");
    mfma_quad<0, 0>(aq, bq, acc);
    __builtin_amdgcn_s_barrier();

    // ph1: read B-q23; stage B(c+1)h0
    read_bq<1>(rB, lg, lr, bq);
    stage_half(gB, lB, c + 1, 1, 0);
    __builtin_amdgcn_s_barrier();
    asm volatile("s_waitcnt lgkmcnt(0)" ::: "memory");
    mfma_quad<0, 1>(aq, bq, acc);
    __builtin_amdgcn_s_barrier();

    // ph2: read A-q1; stage B(c+1)h1
    read_aq<1>(rA, lg, lr, aq);
    stage_half(gB, lB, c + 1, 1, 1);
    __builtin_amdgcn_s_barrier();
    asm volatile("s_waitcnt lgkmcnt(0)" ::: "memory");
    mfma_quad<1, 0>(aq, bq, acc);
    __builtin_amdgcn_s_barrier();

    // ph3: stage A(c+2)h0 -> slot0 (slot0 A fully read after ph2)
    if (it < 7) stage_half(gA, lA, c + 2, 0, 0);
    __builtin_amdgcn_s_barrier();
    mfma_quad<1, 1>(aq, bq, acc);
    __builtin_amdgcn_s_barrier();

    // W4: slot1 (K-tile c+1) fully landed; ph3's load may fly
    if (it == 7) {
      asm volatile("s_waitcnt vmcnt(0)" ::: "memory");
    } else {
      asm volatile("s_waitcnt vmcnt(2)" ::: "memory");
    }
    __builtin_amdgcn_s_barrier();

    // ph4: read slot1 A-q0 + B-q01; stage A(c+2)h1
    read_aq<0>(rA + 32768, lg, lr, aq);
    read_bq<0>(rB + 32768, lg, lr, bq);
    if (it < 7) stage_half(gA, lA, c + 2, 0, 1);
    __builtin_amdgcn_s_barrier();
    asm volatile("s_waitcnt lgkmcnt(0)" ::: "memory");
    mfma_quad<0, 0>(aq, bq, acc);
    __builtin_amdgcn_s_barrier();

    // ph5: read B-q23; stage B(c+2)h0
    read_bq<1>(rB + 32768, lg, lr, bq);
    if (it < 7) stage_half(gB, lB, c + 2, 0, 0);
    __builtin_amdgcn_s_barrier();
    asm volatile("s_waitcnt lgkmcnt(0)" ::: "memory");
    mfma_quad<0, 1>(aq, bq, acc);
    __builtin_amdgcn_s_barrier();

    // ph6: read A-q1; stage B(c+2)h1
    read_aq<1>(rA + 32768, lg, lr, aq);
    if (it < 7) stage_half(gB, lB, c + 2, 0, 1);
    __builtin_amdgcn_s_barrier();
    asm volatile("s_waitcnt lgkmcnt(0)" ::: "memory");
    mfma_quad<1, 0>(aq, bq, acc);
    __builtin_amdgcn_s_barrier();

    // ph7: stage A(c+3)h0 -> slot1
    if (it < 7) stage_half(gA, lA, c + 3, 1, 0);
    __builtin_amdgcn_s_barrier();
    mfma_quad<1, 1>(aq, bq, acc);
    __builtin_amdgcn_s_barrier();
  }

  // epilogue: QKV scatter (Q scaled; V transposed [b][h][d][t])
#pragma unroll
  for (int i = 0; i < 8; ++i) {
    int mrow0 = mb + wm * 128 + i * 16 + lg * 4;
#pragma unroll
    for (int j = 0; j < 4; ++j) {
      int ncol = nb + wn * 64 + j * 16 + lr;
      int p = ncol >> 10, rem = ncol & 1023, h = rem >> 6, d = rem & 63;
      float sc = (p == 0) ? SCALE_Q : 1.0f;
#pragma unroll
      for (int r = 0; r < 4; ++r) {
        int mrow = mrow0 + r;
        int b = mrow >> 11, t = mrow & 2047;
        size_t off;
        if (p < 2)
          off = ((size_t)((p * B_SZ + b) * NH + h) * T_SEQ + t) * HS + d;
        else
          off = (size_t)(2 * B_SZ * NH) * T_SEQ * HS +
                ((size_t)(b * NH + h) * HS + d) * T_SEQ + t;
        Cout[off] = f2bf(acc[i][j][r] * sc);
      }
    }
  }
}

// ------------- 128x128 GEMM (out-proj): 3-deep counted-vmcnt ---------------
__global__ __launch_bounds__(256, 3) void gemm_proj(
    const unsigned short* __restrict__ A, const unsigned short* __restrict__ Bt,
    float* __restrict__ Cout, const float* __restrict__ bias, int nbx) {
  __shared__ __align__(16) unsigned short As[3][128 * 32];
  __shared__ __align__(16) unsigned short Bs[3][128 * 32];

  const int tid = threadIdx.x;
  const int lane = tid & 63, w = tid >> 6;
  const int wm = w >> 1, wn = w & 1;
  const int lr = lane & 15, lg = lane >> 4;

  const int wg = xcd_swz(blockIdx.x, gridDim.x);
  const int mb = (wg / nbx) * 128, nb = (wg % nbx) * 128;

  v4f acc[4][4];
  v4f zero = {0.f, 0.f, 0.f, 0.f};
#pragma unroll
  for (int i = 0; i < 4; ++i)
#pragma unroll
    for (int j = 0; j < 4; ++j) acc[i][j] = zero;

  const int srow = lane >> 2;
  const int sgcol = ((lane & 3) ^ (srow & 3)) * 8;
  const unsigned short* gA = A + (size_t)(mb + w * 32 + srow) * KSZ + sgcol;
  const unsigned short* gB = Bt + (size_t)(nb + w * 32 + srow) * KSZ + sgcol;
  unsigned short* lA = &As[0][0] + w * 1024;
  unsigned short* lB = &Bs[0][0] + w * 1024;

#define STAGE_G(buf, kb)                                        \
  do {                                                          \
    gload_lds16(gA + (kb), lA + (buf) * 4096);                  \
    gload_lds16(gA + (kb) + 16 * KSZ, lA + (buf) * 4096 + 512); \
    gload_lds16(gB + (kb), lB + (buf) * 4096);                  \
    gload_lds16(gB + (kb) + 16 * KSZ, lB + (buf) * 4096 + 512); \
  } while (0)

  STAGE_G(0, 0);
  STAGE_G(1, 32);
  STAGE_G(2, 64);

  const int NT = KSZ / 32;
  for (int t = 0; t < NT; ++t) {
    asm volatile("s_waitcnt vmcnt(8)" ::: "memory");
    __builtin_amdgcn_s_barrier();

    const int buf = t % 3;
    v8s af[4], bfr[4];
#pragma unroll
    for (int i = 0; i < 4; ++i) {
      int ra = wm * 64 + i * 16 + lr, rb = wn * 64 + i * 16 + lr;
      af[i]  = *(const v8s*)&As[buf][ra * 32 + ((lg ^ (lr & 3)) << 3)];
      bfr[i] = *(const v8s*)&Bs[buf][rb * 32 + ((lg ^ (lr & 3)) << 3)];
    }
#pragma unroll
    for (int i = 0; i < 4; ++i)
#pragma unroll
      for (int j = 0; j < 4; ++j)
        acc[i][j] = __builtin_amdgcn_mfma_f32_16x16x32_bf16(af[i], bfr[j], acc[i][j], 0, 0, 0);

    asm volatile("s_waitcnt lgkmcnt(0)" ::: "memory");
    __builtin_amdgcn_s_barrier();
    if (t + 3 < NT) STAGE_G(buf, (t + 3) * 32);
  }
#undef STAGE_G

#pragma unroll
  for (int i = 0; i < 4; ++i) {
    int mrow0 = mb + wm * 64 + i * 16 + lg * 4;
#pragma unroll
    for (int j = 0; j < 4; ++j) {
      int ncol = nb + wn * 64 + j * 16 + lr;
      float bv = bias[ncol];
#pragma unroll
      for (int r = 0; r < 4; ++r)
        Cout[(size_t)(mrow0 + r) * CEMB + ncol] = acc[i][j][r] + bv;
    }
  }
}

// ------------- causal flash attention, swapped-operand, reg-P -------------
__global__ __launch_bounds__(512, 4) void attn_kernel(
    const unsigned short* __restrict__ Qg, const unsigned short* __restrict__ Kg,
    const unsigned short* __restrict__ Vtg, unsigned short* __restrict__ Yg) {
  __shared__ __align__(16) unsigned char lds[32 * 1024];
  unsigned char* KsB = lds;             // 16KB [128 s][64 d], chunk-swizzled
  unsigned char* VtB = lds + 16384;     // 16KB [64 d][128 col'], swizzled

  const int tid = threadIdx.x;
  const int lane = tid & 63, w = tid >> 6;
  const int lr = lane & 15, lg = lane >> 4;
  const int qc = 15 - (blockIdx.x >> 5);   // LPT: longest q-chunk first
  const int bh = blockIdx.x & 31;

  const unsigned short* Qbase = Qg + (size_t)bh * T_SEQ * HS;
  const unsigned short* Kbase = Kg + (size_t)bh * T_SEQ * HS;
  const unsigned short* Vtbase = Vtg + (size_t)bh * T_SEQ * HS;  // [64][2048]

  const int ks_row = tid >> 3, ks_cb = tid & 7;
  const int kLds0 = ks_row * 128 + ((ks_cb ^ (ks_row & 7)) << 4);
  const unsigned short* Kg0 = Kbase + ks_row * HS + ks_cb * 8;
  const int vs_d = tid >> 4, vs_m = tid & 15;
  const int vLds0 = vs_d * 256 + ((vs_m ^ (vs_d & 15)) << 4);
  const int vbt = ((vs_m >> 2) << 4) + ((vs_m & 3) << 2);
  const unsigned short* Vg0 = Vtbase + (size_t)vs_d * T_SEQ + vbt;

  v8s qA[2];
  {
    const unsigned short* qrow = Qbase + (size_t)(qc * 128 + w * 16 + lr) * HS;
    qA[0] = *(const v8s*)(qrow + lg * 8);
    qA[1] = *(const v8s*)(qrow + 32 + lg * 8);
  }

  v4f O[4];
  v4f zero = {0.f, 0.f, 0.f, 0.f};
#pragma unroll
  for (int d = 0; d < 4; ++d) O[d] = zero;
  float mrun = -1e30f, lrun = 0.f;

  int4 gK0 = *(const int4*)(Kg0);
  int4 gK1 = *(const int4*)(Kg0 + 4096);
  int2 vlo0 = *(const int2*)(Vg0);
  int2 vhi0 = *(const int2*)(Vg0 + 64);
  int2 vlo1 = *(const int2*)(Vg0 + 32 * T_SEQ);
  int2 vhi1 = *(const int2*)(Vg0 + 32 * T_SEQ + 64);

  for (int t = 0; t <= qc; ++t) {
    __syncthreads();
    *(int4*)(KsB + kLds0) = gK0;
    *(int4*)(KsB + kLds0 + 8192) = gK1;
    {
      int4 v0; v0.x = vlo0.x; v0.y = vlo0.y; v0.z = vhi0.x; v0.w = vhi0.y;
      int4 v1; v1.x = vlo1.x; v1.y = vlo1.y; v1.z = vhi1.x; v1.w = vhi1.y;
      *(int4*)(VtB + vLds0) = v0;
      *(int4*)(VtB + vLds0 + 8192) = v1;
    }
    __syncthreads();
    if (t < qc) {
      const unsigned short* kp = Kg0 + (t + 1) * (128 * HS);
      gK0 = *(const int4*)kp;
      gK1 = *(const int4*)(kp + 4096);
      const unsigned short* vp = Vg0 + (t + 1) * 128;
      vlo0 = *(const int2*)(vp);
      vhi0 = *(const int2*)(vp + 64);
      vlo1 = *(const int2*)(vp + 32 * T_SEQ);
      vhi1 = *(const int2*)(vp + 32 * T_SEQ + 64);
    }

    const int cflim = (t == qc) ? w : 7;

    v4f S[8];
    __builtin_amdgcn_s_setprio(1);
#pragma unroll
    for (int cf = 0; cf < 8; ++cf) {
      if (cf <= cflim) {
        S[cf] = zero;
#pragma unroll
        for (int ks = 0; ks < 2; ++ks) {
          int srow = cf * 16 + lr;
          v8s kb = *(const v8s*)(KsB + srow * 128 +
                                 ((((ks << 2) + lg) ^ (lr & 7)) << 4));
          S[cf] = __builtin_amdgcn_mfma_f32_16x16x32_bf16(kb, qA[ks], S[cf], 0, 0, 0);
        }
      } else {
        S[cf] = (v4f){-1e30f, -1e30f, -1e30f, -1e30f};
      }
    }
    __builtin_amdgcn_s_setprio(0);

    if (t == qc) {
#pragma unroll
      for (int cf = 0; cf < 8; ++cf)
        if (cf == w) {
#pragma unroll
          for (int r = 0; r < 4; ++r)
            if (lg * 4 + r > lr) S[cf][r] = -1e30f;
        }
    }

    float mx = -1e30f;
#pragma unroll
    for (int cf = 0; cf < 8; ++cf)
#pragma unroll
      for (int r = 0; r < 4; ++r) mx = fmaxf(mx, S[cf][r]);
    mx = fmaxf(mx, __shfl_xor(mx, 16));
    mx = fmaxf(mx, __shfl_xor(mx, 32));

    if (!__all(mx - mrun <= 8.0f)) {     // defer-max (T13, THR=8)
      float mn = fmaxf(mrun, mx);
      float alpha = exp2_fast(mrun - mn);
      mrun = mn;
      lrun *= alpha;
#pragma unroll
      for (int df = 0; df < 4; ++df)
#pragma unroll
        for (int r = 0; r < 4; ++r) O[df][r] *= alpha;
    }

    float sum = 0.f;
#pragma unroll
    for (int cf = 0; cf < 8; ++cf)
#pragma unroll
      for (int r = 0; r < 4; ++r) {
        float p = exp2_fast(S[cf][r] - mrun);
        S[cf][r] = p;
        sum += p;
      }
    sum += __shfl_xor(sum, 16);
    sum += __shfl_xor(sum, 32);
    lrun += sum;

    unsigned pk0[8], pk1[8];
#pragma unroll
    for (int cf = 0; cf < 8; ++cf) {
      pk0[cf] = cvt_pk_bf16(S[cf][0], S[cf][1]);
      pk1[cf] = cvt_pk_bf16(S[cf][2], S[cf][3]);
    }

    __builtin_amdgcn_s_setprio(1);
#pragma unroll
    for (int c = 0; c < 4; ++c) {
      if (t != qc || c <= w) {
        union { unsigned u[4]; v8s s; } pu;
        pu.u[0] = pk0[c]; pu.u[1] = pk1[c];
        pu.u[2] = pk0[c + 4]; pu.u[3] = pk1[c + 4];
        v8s pa = pu.s;
#pragma unroll
        for (int df = 0; df < 4; ++df) {
          int d = df * 16 + lr;
          v8s va = *(const v8s*)(VtB + d * 256 +
                                 ((((c << 2) + lg) ^ lr) << 4));
          O[df] = __builtin_amdgcn_mfma_f32_16x16x32_bf16(va, pa, O[df], 0, 0, 0);
        }
      }
    }
    __builtin_amdgcn_s_setprio(0);
  }

  float invl = 1.0f / lrun;
  int tq = qc * 128 + w * 16 + lr;
  int b = bh >> 4, h = bh & 15;
  size_t ybase = ((size_t)b * T_SEQ + tq) * (NH * HS) + h * 64;
#pragma unroll
  for (int df = 0; df < 4; ++df) {
    ushort4 o4;
    o4.x = f2bf(O[df][0] * invl);
    o4.y = f2bf(O[df][1] * invl);
    o4.z = f2bf(O[df][2] * invl);
    o4.w = f2bf(O[df][3] * invl);
    *(ushort4*)(Yg + ybase + df * 16 + lg * 4) = o4;
  }
}

extern "C" void kernel_launch(void* const* d_in, const int* in_sizes, int n_in,
                              void* d_out, int out_size, void* d_ws, size_t ws_size,
                              hipStream_t stream) {
  (void)in_sizes; (void)n_in; (void)out_size; (void)ws_size;
  const float* x  = (const float*)d_in[0];
  const float* Wq = (const float*)d_in[1];
  const float* Wk = (const float*)d_in[2];
  const float* Wv = (const float*)d_in[3];
  const float* Wo = (const float*)d_in[4];
  const float* bo = (const float*)d_in[5];

  unsigned char* ws = (unsigned char*)d_ws;
  unsigned short* xb  = (unsigned short*)(ws);                      // 8MB
  unsigned short* Wt  = (unsigned short*)(ws + (8u << 20));         // 6MB
  unsigned short* Wot = (unsigned short*)(ws + (14u << 20));        // 2MB
  unsigned short* qkv = (unsigned short*)(ws + (16u << 20));        // 24MB
  unsigned short* Y   = (unsigned short*)(ws + (40u << 20));        // 8MB

  // 1. fused prep: x->bf16 + all weight transposes (one launch)
  prep_kernel<<<dim3(6144), 256, 0, stream>>>(x, Wq, Wk, Wv, Wo, xb, Wt, Wot);

  // 2. fused QKV projection: 256^2 8-phase (192 blocks, 16x12)
  gemm256<<<dim3(192), 512, 0, stream>>>(xb, Wt, qkv, 12);

  // 3. causal flash attention (V pre-transposed per head: [b][h][64][2048])
  const unsigned short* Qp = qkv;
  const unsigned short* Kp = qkv + (size_t)B_SZ * NH * T_SEQ * HS;
  const unsigned short* Vtp = qkv + (size_t)2 * B_SZ * NH * T_SEQ * HS;
  attn_kernel<<<dim3(512), 512, 0, stream>>>(Qp, Kp, Vtp, Y);

  // 4. output projection + bias -> f32 d_out (256 blocks, 32x8)
  gemm_proj<<<dim3(256), 256, 0, stream>>>(Y, Wot, (float*)d_out, bo, 8);
}

// Round 9
// 99.492 us; speedup vs baseline: 1.2417x; 1.2417x over previous
//
#include <hip/hip_runtime.h>

// MHA forward, full-bf16 MFMA pipeline.
// ws layout (bytes): xb[8MB] | Wt[6MB: [3][1024][1024] bf16 N-major] | Wot[2MB]
//                    | qkv[24MB: Q,K:[B][H][T][64], V:[B][H][64][T]] | Y[8MB]

typedef short v8s __attribute__((ext_vector_type(8)));
typedef float v4f __attribute__((ext_vector_type(4)));

#define DEVI __device__ __forceinline__

#define B_SZ 2
#define T_SEQ 2048
#define NH 16
#define HS 64
#define CEMB 1024
#define MROWS (B_SZ * T_SEQ)   // 4096
#define KSZ 1024
// Q scale: 1/sqrt(64) * log2(e)  (attention softmax runs in exp2 domain)
#define SCALE_Q 0.18033688011112042f

DEVI unsigned short f2bf(float f) {
  union { float f; unsigned u; } c; c.f = f;
  unsigned u = c.u;
  unsigned r = (u + 0x7FFFu + ((u >> 16) & 1u)) >> 16;   // RNE
  return (unsigned short)r;
}

DEVI float exp2_fast(float x) {         // v_exp_f32 = 2^x
  float r;
  asm("v_exp_f32 %0, %1" : "=v"(r) : "v"(x));
  return r;
}

DEVI unsigned cvt_pk_bf16(float lo, float hi) {  // packs 2 f32 -> 2 bf16 (RNE)
  unsigned r;
  asm("v_cvt_pk_bf16_f32 %0, %1, %2" : "=v"(r) : "v"(lo), "v"(hi));
  return r;
}

// async global -> LDS, 16B per lane (wave-uniform LDS base + lane*16)
DEVI void gload_lds16(const void* g, void* l) {
  __builtin_amdgcn_global_load_lds(
      (const __attribute__((address_space(1))) void*)g,
      (__attribute__((address_space(3))) void*)l, 16, 0, 0);
}

// bijective XCD-contiguous block swizzle (requires nwg % 8 == 0)
DEVI int xcd_swz(int bid, int nwg) {
  int q = nwg >> 3;
  return (bid & 7) * q + (bid >> 3);
}

// ---------------- fused prep: x->bf16 + weight transposes (1 launch) -------
__global__ __launch_bounds__(256, 4) void prep_kernel(
    const float* __restrict__ x, const float* __restrict__ Wq,
    const float* __restrict__ Wk, const float* __restrict__ Wv,
    const float* __restrict__ Wo, unsigned short* __restrict__ xb,
    unsigned short* __restrict__ Wt, unsigned short* __restrict__ Wot) {
  int bid = blockIdx.x;
  if (bid < 2048) {
    int i = bid * 2048 + threadIdx.x * 8;
    float4 a = *(const float4*)(x + i);
    float4 b = *(const float4*)(x + i + 4);
    ushort4 o0, o1;
    o0.x = f2bf(a.x); o0.y = f2bf(a.y); o0.z = f2bf(a.z); o0.w = f2bf(a.w);
    o1.x = f2bf(b.x); o1.y = f2bf(b.y); o1.z = f2bf(b.z); o1.w = f2bf(b.w);
    *(ushort4*)(xb + i) = o0;
    *(ushort4*)(xb + i + 4) = o1;
    return;
  }
  __shared__ float tile[32][33];
  const float* in; unsigned short* out;
  int C, bx, by;
  if (bid < 5120) {
    int b2 = bid - 2048;
    int widx = b2 >> 10, rem = b2 & 1023;
    in = (widx == 0 ? Wq : (widx == 1 ? Wk : Wv));
    int z = rem >> 6;                     // head 0..15
    bx = rem & 1; by = (rem >> 1) & 31;
    C = 64;
    in += (size_t)z * 1024 * 64;
    out = Wt + ((size_t)widx << 20) + (size_t)z * 1024 * 64;
  } else {
    int rem = bid - 5120;
    C = 1024;
    bx = rem & 31; by = rem >> 5;
    in = Wo; out = Wot;
  }
  int c0 = bx * 32, r0 = by * 32;
  int tx = threadIdx.x & 31, ty = threadIdx.x >> 5;
#pragma unroll
  for (int j = 0; j < 4; ++j)
    tile[ty + j * 8][tx] = in[(size_t)(r0 + ty + j * 8) * C + c0 + tx];
  __syncthreads();
#pragma unroll
  for (int j = 0; j < 4; ++j)
    out[(size_t)(c0 + ty + j * 8) * 1024 + r0 + tx] = f2bf(tile[tx][ty + j * 8]);
}

// ------------- GEMM: C = A[M][1024] x Bt[N][1024]^T, bf16 in, f32 acc -------
// 128x128 tile, BK=32, 4 waves; 3-deep counted-vmcnt pipeline with CORRECT
// tail peel (vmcnt 8/4/0 at t<NT-2 / NT-2 / NT-1). 1D grid + XCD swizzle.
// LDS linear for global_load_lds; source chunk pre-swizzled (c ^= row&3) +
// same XOR on fragment reads (rule #21 involution).
// MODE 0: QKV epilogue. N-panels: [0,8)=Q (scaled, direct), [8,16)=K (direct),
//   [16,24)=V -> LDS-transpose epilogue: packed b32 writes into a 32KB
//   [128 d][128 t] swizzled tile, then 16B-contiguous stores along t
//   (fixes the 2B/4KB-stride V scatter: 64 -> ~8 L2 lines per store instr).
// MODE 1: out-proj epilogue -> f32 [M][1024] + bias (coalesced).
template <int MODE>
__global__ __launch_bounds__(256, 3) void gemm_bt(
    const unsigned short* __restrict__ A, const unsigned short* __restrict__ Bt,
    void* __restrict__ Cout, const float* __restrict__ bias, int nbx) {
  __shared__ __align__(16) unsigned char lds[49152];     // As[3]|Bs[3] / Vt_l
  unsigned short* As = (unsigned short*)lds;             // [3][4096]
  unsigned short* Bs = (unsigned short*)(lds + 24576);   // [3][4096]

  const int tid = threadIdx.x;
  const int lane = tid & 63, w = tid >> 6;
  const int wm = w >> 1, wn = w & 1;
  const int lr = lane & 15, lg = lane >> 4;

  const int wg = xcd_swz(blockIdx.x, gridDim.x);
  const int mb = (wg / nbx) * 128, nb = (wg % nbx) * 128;

  v4f acc[4][4];
  v4f zero = {0.f, 0.f, 0.f, 0.f};
#pragma unroll
  for (int i = 0; i < 4; ++i)
#pragma unroll
    for (int j = 0; j < 4; ++j) acc[i][j] = zero;

  // staging: wave w covers tile rows w*32..w*32+31 (2 issues/matrix, 16 rows ea)
  const int srow = lane >> 2;
  const int sgcol = ((lane & 3) ^ (srow & 3)) * 8;
  const unsigned short* gA = A + (size_t)(mb + w * 32 + srow) * KSZ + sgcol;
  const unsigned short* gB = Bt + (size_t)(nb + w * 32 + srow) * KSZ + sgcol;
  unsigned short* lA = As + w * 1024;   // wave-uniform; +4096/buf
  unsigned short* lB = Bs + w * 1024;

#define STAGE_G(buf, kb)                                        \
  do {                                                          \
    gload_lds16(gA + (kb), lA + (buf) * 4096);                  \
    gload_lds16(gA + (kb) + 16 * KSZ, lA + (buf) * 4096 + 512); \
    gload_lds16(gB + (kb), lB + (buf) * 4096);                  \
    gload_lds16(gB + (kb) + 16 * KSZ, lB + (buf) * 4096 + 512); \
  } while (0)

  // prologue: 3 tiles in flight (12 loads)
  STAGE_G(0, 0);
  STAGE_G(1, 32);
  STAGE_G(2, 64);

  const int NT = KSZ / 32;   // 32 K-steps
  for (int t = 0; t < NT; ++t) {
    // tile t's 4 loads complete; tail peel keeps the guarantee when fewer
    // than 8 loads remain outstanding (latent race in earlier rounds).
    if (t < NT - 2)
      asm volatile("s_waitcnt vmcnt(8)" ::: "memory");
    else if (t == NT - 2)
      asm volatile("s_waitcnt vmcnt(4)" ::: "memory");
    else
      asm volatile("s_waitcnt vmcnt(0)" ::: "memory");
    __builtin_amdgcn_s_barrier();

    const int buf = t % 3;
    v8s af[4], bfr[4];
#pragma unroll
    for (int i = 0; i < 4; ++i) {
      int ra = wm * 64 + i * 16 + lr, rb = wn * 64 + i * 16 + lr;
      af[i]  = *(const v8s*)&As[buf * 4096 + ra * 32 + ((lg ^ (lr & 3)) << 3)];
      bfr[i] = *(const v8s*)&Bs[buf * 4096 + rb * 32 + ((lg ^ (lr & 3)) << 3)];
    }
#pragma unroll
    for (int i = 0; i < 4; ++i)
#pragma unroll
      for (int j = 0; j < 4; ++j)
        acc[i][j] = __builtin_amdgcn_mfma_f32_16x16x32_bf16(af[i], bfr[j], acc[i][j], 0, 0, 0);

    // all waves done reading buf before overwriting it with tile t+3
    asm volatile("s_waitcnt lgkmcnt(0)" ::: "memory");
    __builtin_amdgcn_s_barrier();
    if (t + 3 < NT) STAGE_G(buf, (t + 3) * 32);
  }
#undef STAGE_G

  if (MODE == 0 && (wg % nbx) >= 16) {
    // ---- V-block epilogue: LDS transpose then t-contiguous 16B stores ----
    // Vt_l: bf16 [128 d][128 t], chunk-XOR swizzle (tc ^= d&15).
    unsigned short* out = (unsigned short*)Cout;
#pragma unroll
    for (int i = 0; i < 4; ++i) {
      int tl0 = wm * 64 + i * 16 + lg * 4;     // local t base (r = +0..3)
      int tc = tl0 >> 3, off = (tl0 & 7) * 2;  // off in {0,8}
#pragma unroll
      for (int j = 0; j < 4; ++j) {
        int dl = wn * 64 + j * 16 + lr;        // local d
        unsigned lo = cvt_pk_bf16(acc[i][j][0], acc[i][j][1]);
        unsigned hi = cvt_pk_bf16(acc[i][j][2], acc[i][j][3]);
        unsigned char* p = lds + dl * 256 + ((tc ^ (dl & 15)) << 4) + off;
        *(unsigned*)p = lo;
        *(unsigned*)(p + 4) = hi;
      }
    }
    __syncthreads();
    int b = mb >> 11, mt = mb & 2047;
    int nrem0 = nb & 1023;
    unsigned short* Vg = out + (size_t)(2 * B_SZ * NH) * T_SEQ * HS;
#pragma unroll
    for (int it = 0; it < 8; ++it) {
      int dl = it * 16 + (tid >> 4);
      int tc = tid & 15;
      const unsigned char* p = lds + dl * 256 + ((tc ^ (dl & 15)) << 4);
      int4 vv = *(const int4*)p;
      int nrem = nrem0 + dl;
      int h = nrem >> 6, dd = nrem & 63;
      *(int4*)(Vg + ((size_t)(b * NH + h) * HS + dd) * T_SEQ + mt + tc * 8) = vv;
    }
    return;
  }

#pragma unroll
  for (int i = 0; i < 4; ++i) {
    int mrow0 = mb + wm * 64 + i * 16 + lg * 4;
#pragma unroll
    for (int j = 0; j < 4; ++j) {
      int ncol = nb + wn * 64 + j * 16 + lr;
      if (MODE == 0) {
        // Q/K panels only (p in {0,1}); 16-lane-contiguous 32B runs
        int p = ncol >> 10, rem = ncol & 1023, h = rem >> 6, d = rem & 63;
        float sc = (p == 0) ? SCALE_Q : 1.0f;
        unsigned short* out = (unsigned short*)Cout;
#pragma unroll
        for (int r = 0; r < 4; ++r) {
          int mrow = mrow0 + r;
          int b = mrow >> 11, t = mrow & 2047;
          out[((size_t)((p * B_SZ + b) * NH + h) * T_SEQ + t) * HS + d] =
              f2bf(acc[i][j][r] * sc);
        }
      } else {
        float* out = (float*)Cout;
        float bv = bias[ncol];
#pragma unroll
        for (int r = 0; r < 4; ++r)
          out[(size_t)(mrow0 + r) * CEMB + ncol] = acc[i][j][r] + bv;
      }
    }
  }
}

// ------------- causal flash attention, swapped-operand, reg-P -------------
// 512 threads = 8 waves; wave w owns q rows qc*128 + w*16 .. +15.
// mfma(K,Q) -> S^T: lane owns ONE q-row (q=w*16+lr), kv = cf*16+lg*4+r.
// PV uses a custom k-slot mapping: B-frag = lane-local packed
// {pk(S[c]),pk(S[c+4])} (no cross-lane, no P LDS); A-frag contiguous via
// permuted V layout in LDS, chunk-XOR swizzled.
__global__ __launch_bounds__(512, 4) void attn_kernel(
    const unsigned short* __restrict__ Qg, const unsigned short* __restrict__ Kg,
    const unsigned short* __restrict__ Vtg, unsigned short* __restrict__ Yg) {
  __shared__ __align__(16) unsigned char lds[32 * 1024];
  unsigned char* KsB = lds;             // 16KB [128 s][64 d], chunk-swizzled
  unsigned char* VtB = lds + 16384;     // 16KB [64 d][128 col'], swizzled

  const int tid = threadIdx.x;
  const int lane = tid & 63, w = tid >> 6;
  const int lr = lane & 15, lg = lane >> 4;
  const int qc = 15 - (blockIdx.x >> 5);   // LPT: longest q-chunk first
  const int bh = blockIdx.x & 31;

  const unsigned short* Qbase = Qg + (size_t)bh * T_SEQ * HS;
  const unsigned short* Kbase = Kg + (size_t)bh * T_SEQ * HS;
  const unsigned short* Vtbase = Vtg + (size_t)bh * T_SEQ * HS;  // [64][2048]

  const int ks_row = tid >> 3, ks_cb = tid & 7;
  const int kLds0 = ks_row * 128 + ((ks_cb ^ (ks_row & 7)) << 4);
  const unsigned short* Kg0 = Kbase + ks_row * HS + ks_cb * 8;
  const int vs_d = tid >> 4, vs_m = tid & 15;
  const int vLds0 = vs_d * 256 + ((vs_m ^ (vs_d & 15)) << 4);
  const int vbt = ((vs_m >> 2) << 4) + ((vs_m & 3) << 2);
  const unsigned short* Vg0 = Vtbase + (size_t)vs_d * T_SEQ + vbt;

  v8s qA[2];
  {
    const unsigned short* qrow = Qbase + (size_t)(qc * 128 + w * 16 + lr) * HS;
    qA[0] = *(const v8s*)(qrow + lg * 8);
    qA[1] = *(const v8s*)(qrow + 32 + lg * 8);
  }

  v4f O[4];
  v4f zero = {0.f, 0.f, 0.f, 0.f};
#pragma unroll
  for (int d = 0; d < 4; ++d) O[d] = zero;
  float mrun = -1e30f, lrun = 0.f;

  int4 gK0 = *(const int4*)(Kg0);
  int4 gK1 = *(const int4*)(Kg0 + 4096);
  int2 vlo0 = *(const int2*)(Vg0);
  int2 vhi0 = *(const int2*)(Vg0 + 64);
  int2 vlo1 = *(const int2*)(Vg0 + 32 * T_SEQ);
  int2 vhi1 = *(const int2*)(Vg0 + 32 * T_SEQ + 64);

  for (int t = 0; t <= qc; ++t) {
    __syncthreads();
    *(int4*)(KsB + kLds0) = gK0;
    *(int4*)(KsB + kLds0 + 8192) = gK1;
    {
      int4 v0; v0.x = vlo0.x; v0.y = vlo0.y; v0.z = vhi0.x; v0.w = vhi0.y;
      int4 v1; v1.x = vlo1.x; v1.y = vlo1.y; v1.z = vhi1.x; v1.w = vhi1.y;
      *(int4*)(VtB + vLds0) = v0;
      *(int4*)(VtB + vLds0 + 8192) = v1;
    }
    __syncthreads();
    if (t < qc) {
      const unsigned short* kp = Kg0 + (t + 1) * (128 * HS);
      gK0 = *(const int4*)kp;
      gK1 = *(const int4*)(kp + 4096);
      const unsigned short* vp = Vg0 + (t + 1) * 128;
      vlo0 = *(const int2*)(vp);
      vhi0 = *(const int2*)(vp + 64);
      vlo1 = *(const int2*)(vp + 32 * T_SEQ);
      vhi1 = *(const int2*)(vp + 32 * T_SEQ + 64);
    }

    const int cflim = (t == qc) ? w : 7;

    v4f S[8];
    __builtin_amdgcn_s_setprio(1);
#pragma unroll
    for (int cf = 0; cf < 8; ++cf) {
      if (cf <= cflim) {
        S[cf] = zero;
#pragma unroll
        for (int ks = 0; ks < 2; ++ks) {
          int srow = cf * 16 + lr;
          v8s kb = *(const v8s*)(KsB + srow * 128 +
                                 ((((ks << 2) + lg) ^ (lr & 7)) << 4));
          S[cf] = __builtin_amdgcn_mfma_f32_16x16x32_bf16(kb, qA[ks], S[cf], 0, 0, 0);
        }
      } else {
        S[cf] = (v4f){-1e30f, -1e30f, -1e30f, -1e30f};
      }
    }
    __builtin_amdgcn_s_setprio(0);

    if (t == qc) {
#pragma unroll
      for (int cf = 0; cf < 8; ++cf)
        if (cf == w) {
#pragma unroll
          for (int r = 0; r < 4; ++r)
            if (lg * 4 + r > lr) S[cf][r] = -1e30f;
        }
    }

    float mx = -1e30f;
#pragma unroll
    for (int cf = 0; cf < 8; ++cf)
#pragma unroll
      for (int r = 0; r < 4; ++r) mx = fmaxf(mx, S[cf][r]);
    mx = fmaxf(mx, __shfl_xor(mx, 16));
    mx = fmaxf(mx, __shfl_xor(mx, 32));

    if (!__all(mx - mrun <= 8.0f)) {     // defer-max (T13, THR=8)
      float mn = fmaxf(mrun, mx);
      float alpha = exp2_fast(mrun - mn);
      mrun = mn;
      lrun *= alpha;
#pragma unroll
      for (int df = 0; df < 4; ++df)
#pragma unroll
        for (int r = 0; r < 4; ++r) O[df][r] *= alpha;
    }

    float sum = 0.f;
#pragma unroll
    for (int cf = 0; cf < 8; ++cf)
#pragma unroll
      for (int r = 0; r < 4; ++r) {
        float p = exp2_fast(S[cf][r] - mrun);
        S[cf][r] = p;
        sum += p;
      }
    sum += __shfl_xor(sum, 16);
    sum += __shfl_xor(sum, 32);
    lrun += sum;

    unsigned pk0[8], pk1[8];
#pragma unroll
    for (int cf = 0; cf < 8; ++cf) {
      pk0[cf] = cvt_pk_bf16(S[cf][0], S[cf][1]);
      pk1[cf] = cvt_pk_bf16(S[cf][2], S[cf][3]);
    }

    __builtin_amdgcn_s_setprio(1);
#pragma unroll
    for (int c = 0; c < 4; ++c) {
      if (t != qc || c <= w) {
        union { unsigned u[4]; v8s s; } pu;
        pu.u[0] = pk0[c]; pu.u[1] = pk1[c];
        pu.u[2] = pk0[c + 4]; pu.u[3] = pk1[c + 4];
        v8s pa = pu.s;
#pragma unroll
        for (int df = 0; df < 4; ++df) {
          int d = df * 16 + lr;
          v8s va = *(const v8s*)(VtB + d * 256 +
                                 ((((c << 2) + lg) ^ lr) << 4));
          O[df] = __builtin_amdgcn_mfma_f32_16x16x32_bf16(va, pa, O[df], 0, 0, 0);
        }
      }
    }
    __builtin_amdgcn_s_setprio(0);
  }

  float invl = 1.0f / lrun;
  int tq = qc * 128 + w * 16 + lr;
  int b = bh >> 4, h = bh & 15;
  size_t ybase = ((size_t)b * T_SEQ + tq) * (NH * HS) + h * 64;
#pragma unroll
  for (int df = 0; df < 4; ++df) {
    ushort4 o4;
    o4.x = f2bf(O[df][0] * invl);
    o4.y = f2bf(O[df][1] * invl);
    o4.z = f2bf(O[df][2] * invl);
    o4.w = f2bf(O[df][3] * invl);
    *(ushort4*)(Yg + ybase + df * 16 + lg * 4) = o4;
  }
}

extern "C" void kernel_launch(void* const* d_in, const int* in_sizes, int n_in,
                              void* d_out, int out_size, void* d_ws, size_t ws_size,
                              hipStream_t stream) {
  (void)in_sizes; (void)n_in; (void)out_size; (void)ws_size;
  const float* x  = (const float*)d_in[0];
  const float* Wq = (const float*)d_in[1];
  const float* Wk = (const float*)d_in[2];
  const float* Wv = (const float*)d_in[3];
  const float* Wo = (const float*)d_in[4];
  const float* bo = (const float*)d_in[5];

  unsigned char* ws = (unsigned char*)d_ws;
  unsigned short* xb  = (unsigned short*)(ws);                      // 8MB
  unsigned short* Wt  = (unsigned short*)(ws + (8u << 20));         // 6MB
  unsigned short* Wot = (unsigned short*)(ws + (14u << 20));        // 2MB
  unsigned short* qkv = (unsigned short*)(ws + (16u << 20));        // 24MB
  unsigned short* Y   = (unsigned short*)(ws + (40u << 20));        // 8MB

  // 1. fused prep: x->bf16 + all weight transposes (one launch)
  prep_kernel<<<dim3(6144), 256, 0, stream>>>(x, Wq, Wk, Wv, Wo, xb, Wt, Wot);

  // 2. fused QKV projection: [4096][1024] x [3072][1024]^T (768 blocks)
  gemm_bt<0><<<dim3(768), 256, 0, stream>>>(xb, Wt, qkv, nullptr, 24);

  // 3. causal flash attention (V pre-transposed per head: [b][h][64][2048])
  const unsigned short* Qp = qkv;
  const unsigned short* Kp = qkv + (size_t)B_SZ * NH * T_SEQ * HS;
  const unsigned short* Vtp = qkv + (size_t)2 * B_SZ * NH * T_SEQ * HS;
  attn_kernel<<<dim3(512), 512, 0, stream>>>(Qp, Kp, Vtp, Y);

  // 4. output projection + bias -> f32 d_out (256 blocks)
  gemm_bt<1><<<dim3(256), 256, 0, stream>>>(Y, Wot, d_out, bo, 8);
}